// Round 8
// baseline (726.139 us; speedup 1.0000x reference)
//
#include <hip/hip_runtime.h>
#include <hip/hip_fp16.h>
#include <math.h>

#define T_STEPS 8
#define F_IN    8
#define HID     32
#define KCH     5
#define PERIODS 8
#define NB      64
#define WSLD    140
#define TSLD    68

__device__ __forceinline__ float sigmoidf_(float x) { return 1.f / (1.f + __expf(-x)); }
__device__ __forceinline__ float tanhf_(float x) {
    float e = __expf(2.f * x);
    return 1.f - 2.f / (e + 1.f);
}

// ---------------- graph setup ----------------

__global__ void k_count(const int* __restrict__ src, const int* __restrict__ dst,
                        int* __restrict__ degi, int* __restrict__ cnt, int E) {
    int e = blockIdx.x * blockDim.x + threadIdx.x;
    if (e >= E) return;
    int s = src[e], d = dst[e];
    if (s != d) {
        atomicAdd(&degi[s], 1);
        atomicAdd(&cnt[d], 1);
    }
}

// block-local degree histogram, bin-major output: hist[bin*NT + blk]
__global__ void k_hist2(const int* __restrict__ cnt, int* __restrict__ hist,
                        int N, int NT) {
    __shared__ int h[256];
    int tid = threadIdx.x, blk = blockIdx.x;
    h[tid] = 0;
    __syncthreads();
    int n = blk * 256 + tid;
    if (n < N) atomicAdd(&h[min(cnt[n], 255)], 1);
    __syncthreads();
    hist[tid * NT + blk] = h[tid];
}

// exclusive scan, single block 1024 threads, 32 elems/thread; valid n <= 32768
__global__ void __launch_bounds__(1024) k_scan(const int* __restrict__ in,
                                               int* __restrict__ outp, int n) {
    __shared__ int wsum[16];
    int tid = threadIdx.x;
    int base = tid * 32;
    int v[32];
    int s = 0;
    #pragma unroll
    for (int i = 0; i < 32; ++i) {
        int idx = base + i;
        int t = (idx < n) ? in[idx] : 0;
        v[i] = t; s += t;
    }
    int lane = tid & 63, wave = tid >> 6;
    int incl = s;
    #pragma unroll
    for (int off = 1; off < 64; off <<= 1) {
        int t = __shfl_up(incl, off, 64);
        if (lane >= off) incl += t;
    }
    if (lane == 63) wsum[wave] = incl;
    __syncthreads();
    if (tid < 64) {
        int w = (tid < 16) ? wsum[tid] : 0;
        int iw = w;
        #pragma unroll
        for (int off = 1; off < 16; off <<= 1) {
            int t = __shfl_up(iw, off, 64);
            if (tid >= off) iw += t;
        }
        if (tid < 16) wsum[tid] = iw - w;
    }
    __syncthreads();
    int excl = wsum[wave] + (incl - s);
    #pragma unroll
    for (int i = 0; i < 32; ++i) {
        int idx = base + i;
        if (idx < n) outp[idx] = excl;
        excl += v[i];
    }
    if (tid == 1023) outp[n] = wsum[15] + incl;
}

// counting-sort scatter with block-local ranks (no global atomics) + dis + cntp
__global__ void k_permscat2(const int* __restrict__ cnt, const int* __restrict__ degi,
                            const int* __restrict__ histbase,
                            int* __restrict__ perm, int* __restrict__ iperm,
                            int* __restrict__ cntp, float* __restrict__ dis,
                            int N, int NT) {
    __shared__ int key[256];
    int tid = threadIdx.x, blk = blockIdx.x;
    int n = blk * 256 + tid;
    int k = (n < N) ? min(cnt[n], 255) : -1;
    key[tid] = k;
    __syncthreads();
    if (n < N) {
        int r = 0;
        for (int j = 0; j < tid; ++j) r += (key[j] == k);
        int pos = histbase[k * NT + blk] + r;
        perm[pos] = n;
        iperm[n] = pos;
        cntp[pos] = cnt[n];
        int dg = degi[n];
        dis[n] = (dg > 0) ? rsqrtf((float)dg) : 0.f;
    }
}

// merged: edge scatter into permuted CSR + x transpose/permute/fp16-pack
__global__ void k_scatxt(const int* __restrict__ src, const int* __restrict__ dst,
                         const float* __restrict__ dis, const int* __restrict__ rowptr,
                         const int* __restrict__ iperm, int* __restrict__ fill,
                         int2* __restrict__ cv, const float* __restrict__ xall,
                         __half* __restrict__ xb, int N, int E) {
    int gsz = (int)(gridDim.x * blockDim.x);
    int gtid = blockIdx.x * blockDim.x + threadIdx.x;
    for (int e = gtid; e < E; e += gsz) {
        int s = src[e], d = dst[e];
        if (s != d) {
            float nv = -dis[s] * dis[d];
            int dp = iperm[d];
            int p = atomicAdd(&fill[dp], 1);
            cv[rowptr[dp] + p] = make_int2(iperm[s], __float_as_int(nv));
        }
    }
    for (int i = gtid; i < N * T_STEPS; i += gsz) {
        int n = i >> 3, t = i & 7;
        float4 a = *(const float4*)(xall + ((size_t)t * N + n) * 8);
        float4 b = *(const float4*)(xall + ((size_t)t * N + n) * 8 + 4);
        __half2 h[4];
        h[0] = __float22half2_rn(make_float2(a.x, a.y));
        h[1] = __float22half2_rn(make_float2(a.z, a.w));
        h[2] = __float22half2_rn(make_float2(b.x, b.y));
        h[3] = __float22half2_rn(make_float2(b.z, b.w));
        *(float4*)(xb + (size_t)iperm[n] * 64 + t * 8) = *(float4*)h;
    }
}

// ---------------- Laplacian: pull CSR, fp16 features, ES-way edge split -----
// out[n][c] = alpha * sum_j val[j]*x[col[j]][c] + beta * xprev[n][c]
template <int C, int ES>
__global__ void __launch_bounds__(256) k_lap_h(__half* __restrict__ outp,
                                               const __half* __restrict__ xin,
                                               const __half* __restrict__ xprev,
                                               float alpha, float beta,
                                               const int* __restrict__ rowptr,
                                               const int2* __restrict__ cv, int N) {
    constexpr int Q = C / 8;
    constexpr int W = Q * ES;
    int idx = blockIdx.x * 256 + threadIdx.x;
    int node = idx / W;
    int r = idx % W;
    int q = r % Q, s = r / Q;
    if (node >= N) return;
    int beg = rowptr[node], end = rowptr[node + 1];
    float a0 = 0.f, a1 = 0.f, a2 = 0.f, a3 = 0.f, a4 = 0.f, a5 = 0.f, a6 = 0.f, a7 = 0.f;
    #pragma unroll 4
    for (int j = beg + s; j < end; j += ES) {
        int2 p = cv[j];
        float nv = __int_as_float(p.y);
        float4 raw = *(const float4*)(xin + (size_t)p.x * C + q * 8);
        const __half2* h = (const __half2*)&raw;
        float2 f0 = __half22float2(h[0]);
        float2 f1 = __half22float2(h[1]);
        float2 f2 = __half22float2(h[2]);
        float2 f3 = __half22float2(h[3]);
        a0 += nv * f0.x; a1 += nv * f0.y; a2 += nv * f1.x; a3 += nv * f1.y;
        a4 += nv * f2.x; a5 += nv * f2.y; a6 += nv * f3.x; a7 += nv * f3.y;
    }
    #pragma unroll
    for (int m = Q; m < W; m <<= 1) {
        a0 += __shfl_xor(a0, m, 64); a1 += __shfl_xor(a1, m, 64);
        a2 += __shfl_xor(a2, m, 64); a3 += __shfl_xor(a3, m, 64);
        a4 += __shfl_xor(a4, m, 64); a5 += __shfl_xor(a5, m, 64);
        a6 += __shfl_xor(a6, m, 64); a7 += __shfl_xor(a7, m, 64);
    }
    if (s != 0) return;
    size_t off = (size_t)node * C + q * 8;
    float r0 = alpha * a0, r1 = alpha * a1, r2 = alpha * a2, r3 = alpha * a3;
    float r4 = alpha * a4, r5 = alpha * a5, r6 = alpha * a6, r7 = alpha * a7;
    if (beta != 0.f) {
        float4 raw = *(const float4*)(xprev + off);
        const __half2* h = (const __half2*)&raw;
        float2 f0 = __half22float2(h[0]);
        float2 f1 = __half22float2(h[1]);
        float2 f2 = __half22float2(h[2]);
        float2 f3 = __half22float2(h[3]);
        r0 += beta * f0.x; r1 += beta * f0.y; r2 += beta * f1.x; r3 += beta * f1.y;
        r4 += beta * f2.x; r5 += beta * f2.y; r6 += beta * f3.x; r7 += beta * f3.y;
    }
    __half2 o[4];
    o[0] = __float22half2_rn(make_float2(r0, r1));
    o[1] = __float22half2_rn(make_float2(r2, r3));
    o[2] = __float22half2_rn(make_float2(r4, r5));
    o[3] = __float22half2_rn(make_float2(r6, r7));
    *(float4*)(outp + off) = *(float4*)o;
}

// ---------------- fused lap#4 + gate GEMM + LSTM pointwise -------------------
// 64 nodes/block, 256 threads. The 4th Chebyshev H-term (TH4 = 2*L(TH3) - TH2)
// is computed in-block into fp32 LDS (Ts4) and consumed directly by GEMM chunk
// k=4 — it never touches global memory. Thread tile 4 nodes x 8 outputs,
// output axis o' = h*4+g so the LSTM pointwise is register-local.
__global__ void __launch_bounds__(256) k_step(
    const __half* __restrict__ xb, const __half* __restrict__ TXB,
    __half* __restrict__ THall, float* __restrict__ Cst,
    const float* __restrict__ Wx, const float* __restrict__ Wh,
    const float* __restrict__ w_c, const float* __restrict__ bg,
    const int* __restrict__ rowptr, const int2* __restrict__ cv,
    int t, int withH, int N) {
    __shared__ float Ws[40 * WSLD];    // 22400 B
    __shared__ float Ts[40 * TSLD];    // 10880 B
    __shared__ float Ts4[32 * TSLD];   //  8704 B (fp32 TH4 pane)
    int tid = threadIdx.x;
    int base = blockIdx.x * NB;
    int og = tid & 15;
    int o0 = og * 8;
    int h0 = og * 2;
    int n0 = (tid >> 4) * 4;
    int wp0 = o0 + 4 * (o0 >> 5);

    // ---- fused lap#4: TH4 for this block's 64 nodes -> Ts4 (fp32) ----
    if (withH) {
        const __half* TH3 = THall + (size_t)3 * N * HID;
        const __half* TH2 = THall + (size_t)2 * N * HID;
        int q = tid & 3, s = (tid >> 2) & 1;
        #pragma unroll
        for (int pass = 0; pass < 2; ++pass) {
            int nl = pass * 32 + (tid >> 3);
            int node = base + nl; if (node >= N) node = N - 1;
            int beg = rowptr[node], end = rowptr[node + 1];
            float a0 = 0.f, a1 = 0.f, a2 = 0.f, a3 = 0.f,
                  a4 = 0.f, a5 = 0.f, a6 = 0.f, a7 = 0.f;
            #pragma unroll 4
            for (int j = beg + s; j < end; j += 2) {
                int2 p = cv[j];
                float nv = __int_as_float(p.y);
                float4 raw = *(const float4*)(TH3 + (size_t)p.x * HID + q * 8);
                const __half2* h = (const __half2*)&raw;
                float2 f0 = __half22float2(h[0]);
                float2 f1 = __half22float2(h[1]);
                float2 f2 = __half22float2(h[2]);
                float2 f3 = __half22float2(h[3]);
                a0 += nv * f0.x; a1 += nv * f0.y; a2 += nv * f1.x; a3 += nv * f1.y;
                a4 += nv * f2.x; a5 += nv * f2.y; a6 += nv * f3.x; a7 += nv * f3.y;
            }
            a0 += __shfl_xor(a0, 4, 64); a1 += __shfl_xor(a1, 4, 64);
            a2 += __shfl_xor(a2, 4, 64); a3 += __shfl_xor(a3, 4, 64);
            a4 += __shfl_xor(a4, 4, 64); a5 += __shfl_xor(a5, 4, 64);
            a6 += __shfl_xor(a6, 4, 64); a7 += __shfl_xor(a7, 4, 64);
            if (s == 0) {
                float4 raw = *(const float4*)(TH2 + (size_t)node * HID + q * 8);
                const __half2* h = (const __half2*)&raw;
                float2 f0 = __half22float2(h[0]);
                float2 f1 = __half22float2(h[1]);
                float2 f2 = __half22float2(h[2]);
                float2 f3 = __half22float2(h[3]);
                int row = q * 8;
                Ts4[(row + 0) * TSLD + nl] = 2.f * a0 - f0.x;
                Ts4[(row + 1) * TSLD + nl] = 2.f * a1 - f0.y;
                Ts4[(row + 2) * TSLD + nl] = 2.f * a2 - f1.x;
                Ts4[(row + 3) * TSLD + nl] = 2.f * a3 - f1.y;
                Ts4[(row + 4) * TSLD + nl] = 2.f * a4 - f2.x;
                Ts4[(row + 5) * TSLD + nl] = 2.f * a5 - f2.y;
                Ts4[(row + 6) * TSLD + nl] = 2.f * a6 - f3.x;
                Ts4[(row + 7) * TSLD + nl] = 2.f * a7 - f3.y;
            }
        }
    }

    float acc[4][8];
    #pragma unroll
    for (int oj = 0; oj < 8; ++oj) {
        float b = bg[(oj & 3) * 32 + h0 + (oj >> 2)];
        #pragma unroll
        for (int nj = 0; nj < 4; ++nj) acc[nj][oj] = b;
    }

    // ---- chunk 0: x-terms (40 rows = 5 k x 8 ch) ----
    for (int i = tid; i < 40 * 128; i += 256) {
        int ci = i >> 7, o = i & 127;
        int k = ci >> 3, c = ci & 7, h = o >> 2, g = o & 3;
        Ws[ci * WSLD + o + 4 * (o >> 5)] = Wx[(((g * KCH + k) * 8) + c) * 32 + h];
    }
    for (int i = tid; i < NB * 5; i += 256) {
        int nl = i / 5, k = i % 5;
        int node = base + nl; if (node >= N) node = N - 1;
        const __half* sp = (k == 0) ? (xb + (size_t)node * 64 + t * 8)
                                    : (TXB + ((size_t)(k - 1) * N + node) * 64 + t * 8);
        float4 raw = *(const float4*)sp;
        const __half2* h = (const __half2*)&raw;
        float2 f0 = __half22float2(h[0]);
        float2 f1 = __half22float2(h[1]);
        float2 f2 = __half22float2(h[2]);
        float2 f3 = __half22float2(h[3]);
        int row = k * 8;
        Ts[(row + 0) * TSLD + nl] = f0.x; Ts[(row + 1) * TSLD + nl] = f0.y;
        Ts[(row + 2) * TSLD + nl] = f1.x; Ts[(row + 3) * TSLD + nl] = f1.y;
        Ts[(row + 4) * TSLD + nl] = f2.x; Ts[(row + 5) * TSLD + nl] = f2.y;
        Ts[(row + 6) * TSLD + nl] = f3.x; Ts[(row + 7) * TSLD + nl] = f3.y;
    }
    __syncthreads();
    #pragma unroll 4
    for (int c = 0; c < 40; ++c) {
        float4 wA = *(const float4*)(Ws + c * WSLD + wp0);
        float4 wB = *(const float4*)(Ws + c * WSLD + wp0 + 4);
        float4 tA = *(const float4*)(Ts + c * TSLD + n0);
        float wv[8] = {wA.x, wA.y, wA.z, wA.w, wB.x, wB.y, wB.z, wB.w};
        float tv[4] = {tA.x, tA.y, tA.z, tA.w};
        #pragma unroll
        for (int nj = 0; nj < 4; ++nj)
            #pragma unroll
            for (int oj = 0; oj < 8; ++oj)
                acc[nj][oj] += tv[nj] * wv[oj];
    }

    // ---- chunks 1..5: H-terms k=0..4 (k=4 reads Ts4) ----
    if (withH) {
        for (int k = 0; k < KCH; ++k) {
            __syncthreads();
            for (int i = tid; i < 32 * 128; i += 256) {
                int ci = i >> 7, o = i & 127;
                int h = o >> 2, g = o & 3;
                Ws[ci * WSLD + o + 4 * (o >> 5)] = Wh[(((g * KCH + k) * 32) + ci) * 32 + h];
            }
            if (k < 4) {
                for (int i = tid; i < NB * 4; i += 256) {
                    int nl = i >> 2, qq = i & 3;
                    int node = base + nl; if (node >= N) node = N - 1;
                    float4 raw = *(const float4*)(THall + ((size_t)k * N + node) * 32 + qq * 8);
                    const __half2* h = (const __half2*)&raw;
                    float2 f0 = __half22float2(h[0]);
                    float2 f1 = __half22float2(h[1]);
                    float2 f2 = __half22float2(h[2]);
                    float2 f3 = __half22float2(h[3]);
                    int row = qq * 8;
                    Ts[(row + 0) * TSLD + nl] = f0.x; Ts[(row + 1) * TSLD + nl] = f0.y;
                    Ts[(row + 2) * TSLD + nl] = f1.x; Ts[(row + 3) * TSLD + nl] = f1.y;
                    Ts[(row + 4) * TSLD + nl] = f2.x; Ts[(row + 5) * TSLD + nl] = f2.y;
                    Ts[(row + 6) * TSLD + nl] = f3.x; Ts[(row + 7) * TSLD + nl] = f3.y;
                }
            }
            __syncthreads();
            const float* Tsrc = (k < 4) ? Ts : Ts4;
            #pragma unroll 4
            for (int c = 0; c < 32; ++c) {
                float4 wA = *(const float4*)(Ws + c * WSLD + wp0);
                float4 wB = *(const float4*)(Ws + c * WSLD + wp0 + 4);
                float4 tA = *(const float4*)(Tsrc + c * TSLD + n0);
                float wv[8] = {wA.x, wA.y, wA.z, wA.w, wB.x, wB.y, wB.z, wB.w};
                float tv[4] = {tA.x, tA.y, tA.z, tA.w};
                #pragma unroll
                for (int nj = 0; nj < 4; ++nj)
                    #pragma unroll
                    for (int oj = 0; oj < 8; ++oj)
                        acc[nj][oj] += tv[nj] * wv[oj];
            }
        }
    }

    // ---- LSTM pointwise, register-local ----
    float wci0 = w_c[h0],      wci1 = w_c[h0 + 1];
    float wcf0 = w_c[32 + h0], wcf1 = w_c[32 + h0 + 1];
    float wco0 = w_c[64 + h0], wco1 = w_c[64 + h0 + 1];
    #pragma unroll
    for (int nj = 0; nj < 4; ++nj) {
        int node = base + n0 + nj;
        if (node < N) {
            size_t idx = (size_t)node * 32 + h0;
            float2 Co = *(const float2*)(Cst + idx);
            float2 Cn2, Hn;
            {
                float I  = sigmoidf_(acc[nj][0] + wci0 * Co.x);
                float F  = sigmoidf_(acc[nj][1] + wcf0 * Co.x);
                float Tg = tanhf_(acc[nj][2]);
                float Cn = F * Co.x + I * Tg;
                float O  = sigmoidf_(acc[nj][3] + wco0 * Cn);
                Cn2.x = Cn; Hn.x = O * tanhf_(Cn);
            }
            {
                float I  = sigmoidf_(acc[nj][4] + wci1 * Co.y);
                float F  = sigmoidf_(acc[nj][5] + wcf1 * Co.y);
                float Tg = tanhf_(acc[nj][6]);
                float Cn = F * Co.y + I * Tg;
                float O  = sigmoidf_(acc[nj][7] + wco1 * Cn);
                Cn2.y = Cn; Hn.y = O * tanhf_(Cn);
            }
            *(float2*)(Cst + idx) = Cn2;
            *(__half2*)(THall + idx) = __float22half2_rn(make_float2(Hn.x, Hn.y));
        }
    }
}

// out[perm[i]][p] = sum_h relu(H[i][h]) * W_lin[p][h] + b_lin[p]
__global__ void k_out(const __half* __restrict__ H, const float* __restrict__ W_lin,
                      const float* __restrict__ b_lin, const int* __restrict__ perm,
                      float* __restrict__ out, int N) {
    int idx = blockIdx.x * blockDim.x + threadIdx.x;
    if (idx >= N * PERIODS) return;
    int i = idx / PERIODS, p = idx % PERIODS;
    float acc = b_lin[p];
    const __half* Hp = H + (size_t)i * HID;
    #pragma unroll
    for (int h = 0; h < HID; ++h)
        acc += fmaxf(__half2float(Hp[h]), 0.f) * W_lin[p * HID + h];
    out[(size_t)perm[i] * PERIODS + p] = acc;
}

// ---------------- launch ----------------

extern "C" void kernel_launch(void* const* d_in, const int* in_sizes, int n_in,
                              void* d_out, int out_size, void* d_ws, size_t ws_size,
                              hipStream_t stream) {
    const float* xall  = (const float*)d_in[0];
    const int*   ei    = (const int*)d_in[1];
    const float* Wx    = (const float*)d_in[2];
    const float* Wh    = (const float*)d_in[3];
    const float* w_c   = (const float*)d_in[4];
    const float* bg    = (const float*)d_in[5];
    const float* W_lin = (const float*)d_in[6];
    const float* b_lin = (const float*)d_in[7];
    float* out = (float*)d_out;

    const int E = in_sizes[1] / 2;
    const int N = in_sizes[0] / (T_STEPS * F_IN);
    const int NT = (N + 255) / 256;
    const int* src = ei;
    const int* dst = ei + E;

    char* p = (char*)d_ws;
    auto carve = [&](size_t bytes) -> void* {
        void* r = (void*)p;
        p += (bytes + 255) & ~(size_t)255;
        return r;
    };
    // zero block: degi, cnt, fill, Cst, THall slice 0 (= H0)
    char* zero_begin = p;
    int*    degi  = (int*)   carve((size_t)N * 4);
    int*    cnt   = (int*)   carve((size_t)N * 4);
    int*    fill  = (int*)   carve((size_t)N * 4);
    float*  Cst   = (float*) carve((size_t)N * HID * 4);
    __half* THall = (__half*)carve((size_t)4 * N * HID * 2);  // slices 0..3 only
    size_t zero_bytes = (size_t)((char*)THall - zero_begin) + (size_t)N * HID * 2;
    int*    hist     = (int*)   carve((size_t)256 * NT * 4);
    int*    histbase = (int*)   carve(((size_t)256 * NT + 1) * 4);
    float*  dis      = (float*) carve((size_t)N * 4);
    int*    perm     = (int*)   carve((size_t)N * 4);
    int*    iperm    = (int*)   carve((size_t)N * 4);
    int*    cntp     = (int*)   carve((size_t)N * 4);
    int*    rowptr   = (int*)   carve((size_t)(N + 1) * 4);
    int2*   cv       = (int2*)  carve((size_t)E * 8);
    __half* xb       = (__half*)carve((size_t)N * 64 * 2);
    __half* TXB      = (__half*)carve((size_t)4 * N * 64 * 2);

    hipMemsetAsync(zero_begin, 0, zero_bytes, stream);

    const int TB = 256;
    const int gE = (E + TB - 1) / TB;
    k_count<<<gE, TB, 0, stream>>>(src, dst, degi, cnt, E);
    k_hist2<<<NT, TB, 0, stream>>>(cnt, hist, N, NT);
    k_scan<<<1, 1024, 0, stream>>>(hist, histbase, 256 * NT);
    k_permscat2<<<NT, TB, 0, stream>>>(cnt, degi, histbase, perm, iperm, cntp, dis, N, NT);
    k_scan<<<1, 1024, 0, stream>>>(cntp, rowptr, N);
    k_scatxt<<<gE, TB, 0, stream>>>(src, dst, dis, rowptr, iperm, fill, cv, xall, xb, N, E);

    // batched x-phase Chebyshev terms over all timesteps (C = 64 halves, ES=4)
    __half* TXB0 = TXB;
    __half* TXB1 = TXB + (size_t)N * 64;
    __half* TXB2 = TXB + (size_t)2 * N * 64;
    __half* TXB3 = TXB + (size_t)3 * N * 64;
    const int lapx_grid = (N * 32 + TB - 1) / TB;   // W = 32 lanes/node
    k_lap_h<64, 4><<<lapx_grid, TB, 0, stream>>>(TXB0, xb,   nullptr, 1.f,  0.f, rowptr, cv, N);
    k_lap_h<64, 4><<<lapx_grid, TB, 0, stream>>>(TXB1, TXB0, xb,      2.f, -1.f, rowptr, cv, N);
    k_lap_h<64, 4><<<lapx_grid, TB, 0, stream>>>(TXB2, TXB1, TXB0,    2.f, -1.f, rowptr, cv, N);
    k_lap_h<64, 4><<<lapx_grid, TB, 0, stream>>>(TXB3, TXB2, TXB1,    2.f, -1.f, rowptr, cv, N);

    const int laph_grid = (N * 16 + TB - 1) / TB;   // W = 16 lanes/node
    const int step_grid = (N + NB - 1) / NB;
    __half* TH0 = THall;
    __half* TH1 = THall + (size_t)N * HID;
    __half* TH2 = THall + (size_t)2 * N * HID;
    __half* TH3 = THall + (size_t)3 * N * HID;

    for (int t = 0; t < T_STEPS; ++t) {
        if (t > 0) {   // H-terms all zero at t=0 (H0 = 0): skip laps
            k_lap_h<HID, 4><<<laph_grid, TB, 0, stream>>>(TH1, TH0, nullptr, 1.f,  0.f, rowptr, cv, N);
            k_lap_h<HID, 4><<<laph_grid, TB, 0, stream>>>(TH2, TH1, TH0,     2.f, -1.f, rowptr, cv, N);
            k_lap_h<HID, 4><<<laph_grid, TB, 0, stream>>>(TH3, TH2, TH1,     2.f, -1.f, rowptr, cv, N);
        }
        k_step<<<step_grid, TB, 0, stream>>>(xb, TXB, THall, Cst, Wx, Wh, w_c, bg,
                                             rowptr, cv, t, (t > 0) ? 1 : 0, N);
    }

    k_out<<<(N * PERIODS + TB - 1) / TB, TB, 0, stream>>>(TH0, W_lin, b_lin, perm, out, N);
}